// Round 1
// baseline (856.818 us; speedup 1.0000x reference)
//
#include <hip/hip_runtime.h>

#define NN 100000
#define NE 1000000
#define HID 64
#define BN_EPS 1e-5f

// ---------------- CSR build (once, reused by all 3 layers) ----------------

__global__ void hist_kernel(const int* __restrict__ col, int* __restrict__ deg) {
    int e = blockIdx.x * 256 + threadIdx.x;
    if (e < NE) atomicAdd(&deg[col[e]], 1);
}

// Single-block exclusive scan of deg[0..NN) -> off[0..NN], plus a working copy `cur`.
__global__ void scan_kernel(const int* __restrict__ deg, int* __restrict__ off,
                            int* __restrict__ cur) {
    __shared__ int sh[1024];
    const int CH = (NN + 1023) / 1024;  // 98
    int t = threadIdx.x;
    int s0 = t * CH;
    int s1 = s0 + CH; if (s1 > NN) s1 = NN;
    int lsum = 0;
    for (int i = s0; i < s1; ++i) lsum += deg[i];
    sh[t] = lsum;
    __syncthreads();
    // Hillis-Steele inclusive scan over 1024 partials
    for (int d = 1; d < 1024; d <<= 1) {
        int v = (t >= d) ? sh[t - d] : 0;
        __syncthreads();
        sh[t] += v;
        __syncthreads();
    }
    int run = sh[t] - lsum;  // exclusive prefix for this thread's chunk
    for (int i = s0; i < s1; ++i) { off[i] = run; cur[i] = run; run += deg[i]; }
    if (t == 1023) off[NN] = sh[1023];  // == NE
}

__global__ void dinv_kernel(const int* __restrict__ deg, float* __restrict__ dinv) {
    int n = blockIdx.x * 256 + threadIdx.x;
    if (n < NN) dinv[n] = rsqrtf((float)(deg[n] + 1));  // +1 self loop; deg>=1 always
}

__global__ void fill_kernel(const int* __restrict__ row, const int* __restrict__ col,
                            const float* __restrict__ dinv, int* __restrict__ cur,
                            int* __restrict__ csr_src, float* __restrict__ csr_w) {
    int e = blockIdx.x * 256 + threadIdx.x;
    if (e >= NE) return;
    int r = row[e], c = col[e];
    int pos = atomicAdd(&cur[c], 1);
    csr_src[pos] = r;
    csr_w[pos] = dinv[r] * dinv[c];
}

// ---------------- Per-layer: aggregate-first (A*X), then fused GEMM+BN+ReLU(+res) ----

// One 64-lane group per node; lane = feature. agg[n][f] = dinv[n]^2*x[n][f] + sum_e w*x[src][f]
template <int K>
__global__ __launch_bounds__(256) void agg_kernel(
    const float* __restrict__ x, const float* __restrict__ dinv,
    const int* __restrict__ off, const int* __restrict__ csr_src,
    const float* __restrict__ csr_w, float* __restrict__ agg) {
    int n = blockIdx.x * 4 + (threadIdx.x >> 6);
    int f = threadIdx.x & 63;
    if (n >= NN || f >= K) return;  // no barriers below -> early return safe
    float di = dinv[n];
    float acc = di * di * x[(size_t)n * K + f];
    int p0 = off[n], p1 = off[n + 1];
    for (int p = p0; p < p1; ++p) {
        int s = csr_src[p];      // wave-uniform (broadcast)
        float w = csr_w[p];      // wave-uniform
        acc = fmaf(w, x[(size_t)s * K + f], acc);  // coalesced K*4B row read
    }
    agg[(size_t)n * K + f] = acc;
}

// out[n][j] = relu((dot(agg[n,:],W[:,j]) + b[j] - mean[j])*rs*gamma[j] + beta[j]) [+ out_prev]
template <int K, bool RES>
__global__ __launch_bounds__(256) void gemm_ep_kernel(
    const float* __restrict__ A, const float* __restrict__ W,
    const float* __restrict__ b, const float* __restrict__ gamma,
    const float* __restrict__ beta, const float* __restrict__ mean,
    const float* __restrict__ var, float* __restrict__ out) {
    __shared__ float xs[4][K];
    int rr = threadIdx.x >> 6;
    int j  = threadIdx.x & 63;
    int n  = blockIdx.x * 4 + rr;
    if (n < NN && j < K) xs[rr][j] = A[(size_t)n * K + j];
    __syncthreads();
    if (n >= NN) return;
    float acc = 0.f;
#pragma unroll
    for (int k = 0; k < K; ++k) acc = fmaf(xs[rr][k], W[k * HID + j], acc);
    float a = gamma[j] * rsqrtf(var[j] + BN_EPS);
    float c = fmaf(b[j] - mean[j], a, beta[j]);
    float v = fmaf(acc, a, c);
    v = fmaxf(v, 0.f);
    if (RES) v += out[(size_t)n * HID + j];  // in-place residual, elementwise-safe
    out[(size_t)n * HID + j] = v;
}

// ---------------- Launch ----------------

static inline size_t align256(size_t x) { return (x + 255) & ~(size_t)255; }

extern "C" void kernel_launch(void* const* d_in, const int* in_sizes, int n_in,
                              void* d_out, int out_size, void* d_ws, size_t ws_size,
                              hipStream_t stream) {
    const float* x0   = (const float*)d_in[0];
    const int*   ei   = (const int*)d_in[1];      // [2, NE]: [0..NE)=row(src), [NE..2NE)=col(dst)
    const float* W1   = (const float*)d_in[2];
    const float* W2   = (const float*)d_in[3];
    const float* W3   = (const float*)d_in[4];
    const float* bb   = (const float*)d_in[5];    // [3,64]
    const float* gam  = (const float*)d_in[6];
    const float* bet  = (const float*)d_in[7];
    const float* rmn  = (const float*)d_in[8];
    const float* rvr  = (const float*)d_in[9];
    float* out = (float*)d_out;

    // workspace carve-up (~35 MB)
    char* w = (char*)d_ws;
    int*   deg     = (int*)w;   w += align256((size_t)NN * 4);
    int*   off     = (int*)w;   w += align256((size_t)(NN + 1) * 4);
    int*   cur     = (int*)w;   w += align256((size_t)NN * 4);
    float* dinv    = (float*)w; w += align256((size_t)NN * 4);
    int*   csr_src = (int*)w;   w += align256((size_t)NE * 4);
    float* csr_w   = (float*)w; w += align256((size_t)NE * 4);
    float* agg     = (float*)w; w += align256((size_t)NN * HID * 4);

    const int* row = ei;
    const int* col = ei + NE;

    dim3 blk(256);
    dim3 grE((NE + 255) / 256);
    dim3 grN((NN + 255) / 256);
    dim3 grN4((NN + 3) / 4);

    // CSR build
    hipMemsetAsync(deg, 0, (size_t)NN * 4, stream);
    hist_kernel<<<grE, blk, 0, stream>>>(col, deg);
    scan_kernel<<<1, 1024, 0, stream>>>(deg, off, cur);
    dinv_kernel<<<grN, blk, 0, stream>>>(deg, dinv);
    fill_kernel<<<grE, blk, 0, stream>>>(row, col, dinv, cur, csr_src, csr_w);

    // Layer 0: K=37, no residual
    agg_kernel<37><<<grN4, blk, 0, stream>>>(x0, dinv, off, csr_src, csr_w, agg);
    gemm_ep_kernel<37, false><<<grN4, blk, 0, stream>>>(agg, W1, bb + 0, gam + 0, bet + 0,
                                                        rmn + 0, rvr + 0, out);
    // Layer 1: K=64, residual
    agg_kernel<64><<<grN4, blk, 0, stream>>>(out, dinv, off, csr_src, csr_w, agg);
    gemm_ep_kernel<64, true><<<grN4, blk, 0, stream>>>(agg, W2, bb + 64, gam + 64, bet + 64,
                                                       rmn + 64, rvr + 64, out);
    // Layer 2: K=64, residual
    agg_kernel<64><<<grN4, blk, 0, stream>>>(out, dinv, off, csr_src, csr_w, agg);
    gemm_ep_kernel<64, true><<<grN4, blk, 0, stream>>>(agg, W3, bb + 128, gam + 128, bet + 128,
                                                       rmn + 128, rvr + 128, out);
}

// Round 2
// 638.081 us; speedup vs baseline: 1.3428x; 1.3428x over previous
//
#include <hip/hip_runtime.h>

#define NN 100000
#define NE 1000000
#define HID 64
#define BN_EPS 1e-5f

// scan geometry: 4 elems/thread, 256 threads/block -> 1024 elems/block
#define SCAN_EPB 1024
#define SCAN_NB ((NN + SCAN_EPB - 1) / SCAN_EPB)  // 98

// ---------------- CSR build (once, reused by all 3 layers) ----------------

__global__ void hist_kernel(const int* __restrict__ col, int* __restrict__ deg) {
    int e = blockIdx.x * 256 + threadIdx.x;
    if (e < NE) atomicAdd(&deg[col[e]], 1);
}

// Pass 1: per-block sums of deg chunks
__global__ __launch_bounds__(256) void scan_part(const int* __restrict__ deg,
                                                 int* __restrict__ partials) {
    __shared__ int sh[256];
    int t = threadIdx.x;
    int base = blockIdx.x * SCAN_EPB + t * 4;
    int s = 0;
    if (base + 3 < NN) {
        int4 v = *(const int4*)(deg + base);
        s = v.x + v.y + v.z + v.w;
    } else {
#pragma unroll
        for (int i = 0; i < 4; ++i) if (base + i < NN) s += deg[base + i];
    }
    sh[t] = s;
    __syncthreads();
    for (int d = 128; d > 0; d >>= 1) {
        if (t < d) sh[t] += sh[t + d];
        __syncthreads();
    }
    if (t == 0) partials[blockIdx.x] = sh[0];
}

// Pass 2: exclusive scan of the 98 partials (single tiny block)
__global__ __launch_bounds__(128) void scan_mid(const int* __restrict__ partials,
                                                int* __restrict__ poff) {
    __shared__ int sh[128];
    int t = threadIdx.x;
    int v = (t < SCAN_NB) ? partials[t] : 0;
    sh[t] = v;
    __syncthreads();
    for (int d = 1; d < 128; d <<= 1) {
        int u = (t >= d) ? sh[t - d] : 0;
        __syncthreads();
        sh[t] += u;
        __syncthreads();
    }
    if (t < SCAN_NB) poff[t] = sh[t] - v;  // exclusive prefix
}

// Pass 3: local rescan + block offset -> off, cur
__global__ __launch_bounds__(256) void scan_fin(const int* __restrict__ deg,
                                                const int* __restrict__ poff,
                                                int* __restrict__ off, int* __restrict__ cur) {
    __shared__ int sh[256];
    int t = threadIdx.x;
    int base = blockIdx.x * SCAN_EPB + t * 4;
    int v0 = 0, v1 = 0, v2 = 0, v3 = 0;
    if (base + 3 < NN) {
        int4 v = *(const int4*)(deg + base);
        v0 = v.x; v1 = v.y; v2 = v.z; v3 = v.w;
    } else {
        if (base + 0 < NN) v0 = deg[base + 0];
        if (base + 1 < NN) v1 = deg[base + 1];
        if (base + 2 < NN) v2 = deg[base + 2];
        if (base + 3 < NN) v3 = deg[base + 3];
    }
    int s = v0 + v1 + v2 + v3;
    sh[t] = s;
    __syncthreads();
    for (int d = 1; d < 256; d <<= 1) {
        int u = (t >= d) ? sh[t - d] : 0;
        __syncthreads();
        sh[t] += u;
        __syncthreads();
    }
    int run = poff[blockIdx.x] + sh[t] - s;  // exclusive prefix of this thread's 4 elems
    if (base + 0 < NN) { off[base + 0] = run; cur[base + 0] = run; run += v0; }
    if (base + 1 < NN) { off[base + 1] = run; cur[base + 1] = run; run += v1; }
    if (base + 2 < NN) { off[base + 2] = run; cur[base + 2] = run; run += v2; }
    if (base + 3 < NN) { off[base + 3] = run; cur[base + 3] = run; run += v3; }
    if (blockIdx.x == 0 && t == 0) off[NN] = NE;  // total degree == NE by construction
}

__global__ void dinv_kernel(const int* __restrict__ deg, float* __restrict__ dinv) {
    int n = blockIdx.x * 256 + threadIdx.x;
    if (n < NN) dinv[n] = rsqrtf((float)(deg[n] + 1));  // +1 self loop
}

__global__ void fill_kernel(const int* __restrict__ row, const int* __restrict__ col,
                            const float* __restrict__ dinv, int* __restrict__ cur,
                            int* __restrict__ csr_src, float* __restrict__ csr_w) {
    int e = blockIdx.x * 256 + threadIdx.x;
    if (e >= NE) return;
    int r = row[e], c = col[e];
    int pos = atomicAdd(&cur[c], 1);
    csr_src[pos] = r;
    csr_w[pos] = dinv[r] * dinv[c];
}

// ---------------- Per-layer: aggregate-first (A*X), then fused GEMM+BN+ReLU(+res) ----

// One 64-lane group per node; lane = feature. agg[n][f] = dinv[n]^2*x[n][f] + sum_e w*x[src][f]
template <int K>
__global__ __launch_bounds__(256) void agg_kernel(
    const float* __restrict__ x, const float* __restrict__ dinv,
    const int* __restrict__ off, const int* __restrict__ csr_src,
    const float* __restrict__ csr_w, float* __restrict__ agg) {
    int n = blockIdx.x * 4 + (threadIdx.x >> 6);
    int f = threadIdx.x & 63;
    if (n >= NN || f >= K) return;  // no barriers below -> early return safe
    float di = dinv[n];
    float acc = di * di * x[(size_t)n * K + f];
    int p0 = off[n], p1 = off[n + 1];
    for (int p = p0; p < p1; ++p) {
        int s = csr_src[p];      // wave-uniform (broadcast)
        float w = csr_w[p];      // wave-uniform
        acc = fmaf(w, x[(size_t)s * K + f], acc);  // coalesced K*4B row read
    }
    agg[(size_t)n * K + f] = acc;
}

// out[n][j] = relu((dot(agg[n,:],W[:,j]) + b[j] - mean[j])*rs*gamma[j] + beta[j]) [+ out_prev]
template <int K, bool RES>
__global__ __launch_bounds__(256) void gemm_ep_kernel(
    const float* __restrict__ A, const float* __restrict__ W,
    const float* __restrict__ b, const float* __restrict__ gamma,
    const float* __restrict__ beta, const float* __restrict__ mean,
    const float* __restrict__ var, float* __restrict__ out) {
    __shared__ float xs[4][K];
    int rr = threadIdx.x >> 6;
    int j  = threadIdx.x & 63;
    int n  = blockIdx.x * 4 + rr;
    if (n < NN && j < K) xs[rr][j] = A[(size_t)n * K + j];
    __syncthreads();
    if (n >= NN) return;
    float acc = 0.f;
#pragma unroll
    for (int k = 0; k < K; ++k) acc = fmaf(xs[rr][k], W[k * HID + j], acc);
    float a = gamma[j] * rsqrtf(var[j] + BN_EPS);
    float c = fmaf(b[j] - mean[j], a, beta[j]);
    float v = fmaf(acc, a, c);
    v = fmaxf(v, 0.f);
    if (RES) v += out[(size_t)n * HID + j];  // in-place residual, elementwise-safe
    out[(size_t)n * HID + j] = v;
}

// ---------------- Launch ----------------

static inline size_t align256(size_t x) { return (x + 255) & ~(size_t)255; }

extern "C" void kernel_launch(void* const* d_in, const int* in_sizes, int n_in,
                              void* d_out, int out_size, void* d_ws, size_t ws_size,
                              hipStream_t stream) {
    const float* x0   = (const float*)d_in[0];
    const int*   ei   = (const int*)d_in[1];      // [2, NE]: [0..NE)=row(src), [NE..2NE)=col(dst)
    const float* W1   = (const float*)d_in[2];
    const float* W2   = (const float*)d_in[3];
    const float* W3   = (const float*)d_in[4];
    const float* bb   = (const float*)d_in[5];    // [3,64]
    const float* gam  = (const float*)d_in[6];
    const float* bet  = (const float*)d_in[7];
    const float* rmn  = (const float*)d_in[8];
    const float* rvr  = (const float*)d_in[9];
    float* out = (float*)d_out;

    // workspace carve-up (~35 MB)
    char* w = (char*)d_ws;
    int*   deg      = (int*)w;   w += align256((size_t)NN * 4);
    int*   off      = (int*)w;   w += align256((size_t)(NN + 1) * 4);
    int*   cur      = (int*)w;   w += align256((size_t)NN * 4);
    float* dinv     = (float*)w; w += align256((size_t)NN * 4);
    int*   partials = (int*)w;   w += align256((size_t)SCAN_NB * 4);
    int*   poff     = (int*)w;   w += align256((size_t)SCAN_NB * 4);
    int*   csr_src  = (int*)w;   w += align256((size_t)NE * 4);
    float* csr_w    = (float*)w; w += align256((size_t)NE * 4);
    float* agg      = (float*)w; w += align256((size_t)NN * HID * 4);

    const int* row = ei;
    const int* col = ei + NE;

    dim3 blk(256);
    dim3 grE((NE + 255) / 256);
    dim3 grN((NN + 255) / 256);
    dim3 grN4((NN + 3) / 4);

    // CSR build
    hipMemsetAsync(deg, 0, (size_t)NN * 4, stream);
    hist_kernel<<<grE, blk, 0, stream>>>(col, deg);
    scan_part<<<SCAN_NB, 256, 0, stream>>>(deg, partials);
    scan_mid<<<1, 128, 0, stream>>>(partials, poff);
    scan_fin<<<SCAN_NB, 256, 0, stream>>>(deg, poff, off, cur);
    dinv_kernel<<<grN, blk, 0, stream>>>(deg, dinv);
    fill_kernel<<<grE, blk, 0, stream>>>(row, col, dinv, cur, csr_src, csr_w);

    // Layer 0: K=37, no residual
    agg_kernel<37><<<grN4, blk, 0, stream>>>(x0, dinv, off, csr_src, csr_w, agg);
    gemm_ep_kernel<37, false><<<grN4, blk, 0, stream>>>(agg, W1, bb + 0, gam + 0, bet + 0,
                                                        rmn + 0, rvr + 0, out);
    // Layer 1: K=64, residual
    agg_kernel<64><<<grN4, blk, 0, stream>>>(out, dinv, off, csr_src, csr_w, agg);
    gemm_ep_kernel<64, true><<<grN4, blk, 0, stream>>>(agg, W2, bb + 64, gam + 64, bet + 64,
                                                       rmn + 64, rvr + 64, out);
    // Layer 2: K=64, residual
    agg_kernel<64><<<grN4, blk, 0, stream>>>(out, dinv, off, csr_src, csr_w, agg);
    gemm_ep_kernel<64, true><<<grN4, blk, 0, stream>>>(agg, W3, bb + 128, gam + 128, bet + 128,
                                                       rmn + 128, rvr + 128, out);
}

// Round 3
// 433.852 us; speedup vs baseline: 1.9749x; 1.4707x over previous
//
#include <hip/hip_runtime.h>

#define NN 100000
#define NE 1000000
#define HID 64
#define BN_EPS 1e-5f

// scan geometry: 4 elems/thread, 256 threads/block -> 1024 elems/block
#define SCAN_EPB 1024
#define SCAN_NB ((NN + SCAN_EPB - 1) / SCAN_EPB)  // 98

// ---------------- CSR build (once, reused by all 3 layers) ----------------

__global__ void hist_kernel(const int* __restrict__ col, int* __restrict__ deg) {
    int e = blockIdx.x * 256 + threadIdx.x;
    if (e < NE) atomicAdd(&deg[col[e]], 1);
}

__global__ __launch_bounds__(256) void scan_part(const int* __restrict__ deg,
                                                 int* __restrict__ partials) {
    __shared__ int sh[256];
    int t = threadIdx.x;
    int base = blockIdx.x * SCAN_EPB + t * 4;
    int s = 0;
    if (base + 3 < NN) {
        int4 v = *(const int4*)(deg + base);
        s = v.x + v.y + v.z + v.w;
    } else {
#pragma unroll
        for (int i = 0; i < 4; ++i) if (base + i < NN) s += deg[base + i];
    }
    sh[t] = s;
    __syncthreads();
    for (int d = 128; d > 0; d >>= 1) {
        if (t < d) sh[t] += sh[t + d];
        __syncthreads();
    }
    if (t == 0) partials[blockIdx.x] = sh[0];
}

__global__ __launch_bounds__(128) void scan_mid(const int* __restrict__ partials,
                                                int* __restrict__ poff) {
    __shared__ int sh[128];
    int t = threadIdx.x;
    int v = (t < SCAN_NB) ? partials[t] : 0;
    sh[t] = v;
    __syncthreads();
    for (int d = 1; d < 128; d <<= 1) {
        int u = (t >= d) ? sh[t - d] : 0;
        __syncthreads();
        sh[t] += u;
        __syncthreads();
    }
    if (t < SCAN_NB) poff[t] = sh[t] - v;  // exclusive prefix
}

__global__ __launch_bounds__(256) void scan_fin(const int* __restrict__ deg,
                                                const int* __restrict__ poff,
                                                int* __restrict__ off, int* __restrict__ cur) {
    __shared__ int sh[256];
    int t = threadIdx.x;
    int base = blockIdx.x * SCAN_EPB + t * 4;
    int v0 = 0, v1 = 0, v2 = 0, v3 = 0;
    if (base + 3 < NN) {
        int4 v = *(const int4*)(deg + base);
        v0 = v.x; v1 = v.y; v2 = v.z; v3 = v.w;
    } else {
        if (base + 0 < NN) v0 = deg[base + 0];
        if (base + 1 < NN) v1 = deg[base + 1];
        if (base + 2 < NN) v2 = deg[base + 2];
        if (base + 3 < NN) v3 = deg[base + 3];
    }
    int s = v0 + v1 + v2 + v3;
    sh[t] = s;
    __syncthreads();
    for (int d = 1; d < 256; d <<= 1) {
        int u = (t >= d) ? sh[t - d] : 0;
        __syncthreads();
        sh[t] += u;
        __syncthreads();
    }
    int run = poff[blockIdx.x] + sh[t] - s;
    if (base + 0 < NN) { off[base + 0] = run; cur[base + 0] = run; run += v0; }
    if (base + 1 < NN) { off[base + 1] = run; cur[base + 1] = run; run += v1; }
    if (base + 2 < NN) { off[base + 2] = run; cur[base + 2] = run; run += v2; }
    if (base + 3 < NN) { off[base + 3] = run; cur[base + 3] = run; run += v3; }
    if (blockIdx.x == 0 && t == 0) off[NN] = NE;
}

__global__ void dinv_kernel(const int* __restrict__ deg, float* __restrict__ dinv) {
    int n = blockIdx.x * 256 + threadIdx.x;
    if (n < NN) dinv[n] = rsqrtf((float)(deg[n] + 1));  // +1 self loop
}

// csr entry: {src_node, float_bits(weight)} interleaved -> one 8B load per edge
__global__ void fill_kernel(const int* __restrict__ row, const int* __restrict__ col,
                            const float* __restrict__ dinv, int* __restrict__ cur,
                            int2* __restrict__ csr) {
    int e = blockIdx.x * 256 + threadIdx.x;
    if (e >= NE) return;
    int r = row[e], c = col[e];
    int pos = atomicAdd(&cur[c], 1);
    int2 v; v.x = r; v.y = __float_as_int(dinv[r] * dinv[c]);
    csr[pos] = v;
}

// Pad x0 [NN,37] -> xp [NN,40] (zero-pad) so gather rows are float4-addressable.
__global__ void pad_kernel(const float* __restrict__ x, float* __restrict__ xp) {
    int i = blockIdx.x * 256 + threadIdx.x;
    if (i >= NN * 40) return;
    int n = i / 40, k = i - n * 40;
    xp[i] = (k < 37) ? x[n * 37 + k] : 0.f;
}

// ---------------- Fused layer: gather-aggregate (float4, 4 edges/wave) + GEMM + BN/ReLU(+res)
// NC = row chunks of float4 (row stride NC*16 bytes), KREAL = true K (<= NC*4)
template <int NC, int KREAL, bool RES>
__global__ __launch_bounds__(256) void layer_kernel(
    const float* __restrict__ xin, const float* __restrict__ dinv,
    const int* __restrict__ off, const int2* __restrict__ csr,
    const float* __restrict__ W, const float* __restrict__ b,
    const float* __restrict__ gamma, const float* __restrict__ beta,
    const float* __restrict__ mean, const float* __restrict__ var,
    const float* __restrict__ res, float* __restrict__ out) {
    __shared__ float xs[4][NC * 4];
    const int rr = threadIdx.x >> 6;   // node slot in block
    const int l  = threadIdx.x & 63;
    const int eg = l >> 4;             // edge group 0..3
    const int c  = l & 15;             // float4 chunk
    const int n  = blockIdx.x * 4 + rr;
    const float4* __restrict__ x4 = (const float4*)xin;

    float4 acc = make_float4(0.f, 0.f, 0.f, 0.f);
    if (n < NN && c < NC) {
        const size_t rowb = (size_t)n * NC;
        if (eg == 0) {  // self-loop term dinv[n]^2 * x[n]
            float di = dinv[n];
            float4 v = x4[rowb + c];
            float d2 = di * di;
            acc.x = d2 * v.x; acc.y = d2 * v.y; acc.z = d2 * v.z; acc.w = d2 * v.w;
        }
        int p1 = off[n + 1];
        int p  = off[n] + eg;
        // 2x unrolled: 2 gathers in flight per lane-quad -> 8 per wave
        for (; p + 4 < p1; p += 8) {
            int2 e0 = csr[p];
            int2 e1 = csr[p + 4];
            float4 v0 = x4[(size_t)e0.x * NC + c];
            float4 v1 = x4[(size_t)e1.x * NC + c];
            float w0 = __int_as_float(e0.y), w1 = __int_as_float(e1.y);
            acc.x = fmaf(w0, v0.x, acc.x); acc.y = fmaf(w0, v0.y, acc.y);
            acc.z = fmaf(w0, v0.z, acc.z); acc.w = fmaf(w0, v0.w, acc.w);
            acc.x = fmaf(w1, v1.x, acc.x); acc.y = fmaf(w1, v1.y, acc.y);
            acc.z = fmaf(w1, v1.z, acc.z); acc.w = fmaf(w1, v1.w, acc.w);
        }
        if (p < p1) {
            int2 e0 = csr[p];
            float4 v0 = x4[(size_t)e0.x * NC + c];
            float w0 = __int_as_float(e0.y);
            acc.x = fmaf(w0, v0.x, acc.x); acc.y = fmaf(w0, v0.y, acc.y);
            acc.z = fmaf(w0, v0.z, acc.z); acc.w = fmaf(w0, v0.w, acc.w);
        }
    }
    // reduce across the 4 edge groups (lanes l, l^16, l^32, l^48)
#pragma unroll
    for (int m = 16; m <= 32; m <<= 1) {
        acc.x += __shfl_xor(acc.x, m);
        acc.y += __shfl_xor(acc.y, m);
        acc.z += __shfl_xor(acc.z, m);
        acc.w += __shfl_xor(acc.w, m);
    }
    if (n < NN && c < NC && eg == 0) *(float4*)&xs[rr][c << 2] = acc;
    __syncthreads();
    if (n >= NN) return;
    // GEMM + epilogue: j = l
    float a  = gamma[l] * rsqrtf(var[l] + BN_EPS);
    float cc = fmaf(b[l] - mean[l], a, beta[l]);
    float s = 0.f;
#pragma unroll
    for (int k = 0; k < KREAL; ++k) s = fmaf(xs[rr][k], W[k * HID + l], s);
    float v = fmaf(s, a, cc);
    v = fmaxf(v, 0.f);
    if (RES) v += res[(size_t)n * HID + l];
    out[(size_t)n * HID + l] = v;
}

// ---------------- Launch ----------------

static inline size_t align256(size_t x) { return (x + 255) & ~(size_t)255; }

extern "C" void kernel_launch(void* const* d_in, const int* in_sizes, int n_in,
                              void* d_out, int out_size, void* d_ws, size_t ws_size,
                              hipStream_t stream) {
    const float* x0   = (const float*)d_in[0];
    const int*   ei   = (const int*)d_in[1];
    const float* W1   = (const float*)d_in[2];
    const float* W2   = (const float*)d_in[3];
    const float* W3   = (const float*)d_in[4];
    const float* bb   = (const float*)d_in[5];
    const float* gam  = (const float*)d_in[6];
    const float* bet  = (const float*)d_in[7];
    const float* rmn  = (const float*)d_in[8];
    const float* rvr  = (const float*)d_in[9];
    float* out = (float*)d_out;

    char* w = (char*)d_ws;
    int*   deg      = (int*)w;   w += align256((size_t)NN * 4);
    int*   off      = (int*)w;   w += align256((size_t)(NN + 1) * 4);
    int*   cur      = (int*)w;   w += align256((size_t)NN * 4);
    float* dinv     = (float*)w; w += align256((size_t)NN * 4);
    int*   partials = (int*)w;   w += align256((size_t)SCAN_NB * 4);
    int*   poff     = (int*)w;   w += align256((size_t)SCAN_NB * 4);
    int2*  csr      = (int2*)w;  w += align256((size_t)NE * 8);
    float* xpad     = (float*)w; w += align256((size_t)NN * 40 * 4);
    float* hA       = (float*)w; w += align256((size_t)NN * HID * 4);
    float* hB       = (float*)w; w += align256((size_t)NN * HID * 4);

    const int* row = ei;
    const int* col = ei + NE;

    dim3 blk(256);
    dim3 grE((NE + 255) / 256);
    dim3 grN((NN + 255) / 256);
    dim3 grN4((NN + 3) / 4);
    dim3 grPad((NN * 40 + 255) / 256);

    // CSR build
    hipMemsetAsync(deg, 0, (size_t)NN * 4, stream);
    hist_kernel<<<grE, blk, 0, stream>>>(col, deg);
    scan_part<<<SCAN_NB, 256, 0, stream>>>(deg, partials);
    scan_mid<<<1, 128, 0, stream>>>(partials, poff);
    scan_fin<<<SCAN_NB, 256, 0, stream>>>(deg, poff, off, cur);
    dinv_kernel<<<grN, blk, 0, stream>>>(deg, dinv);
    fill_kernel<<<grE, blk, 0, stream>>>(row, col, dinv, cur, csr);
    pad_kernel<<<grPad, blk, 0, stream>>>(x0, xpad);

    // Layer 0: padded K=40 rows (real K=37), no residual -> hA
    layer_kernel<10, 37, false><<<grN4, blk, 0, stream>>>(
        xpad, dinv, off, csr, W1, bb + 0, gam + 0, bet + 0, rmn + 0, rvr + 0, nullptr, hA);
    // Layer 1: K=64, residual (+hA) -> hB
    layer_kernel<16, 64, true><<<grN4, blk, 0, stream>>>(
        hA, dinv, off, csr, W2, bb + 64, gam + 64, bet + 64, rmn + 64, rvr + 64, hA, hB);
    // Layer 2: K=64, residual (+hB) -> d_out
    layer_kernel<16, 64, true><<<grN4, blk, 0, stream>>>(
        hB, dinv, off, csr, W3, bb + 128, gam + 128, bet + 128, rmn + 128, rvr + 128, hB, out);
}

// Round 4
// 395.953 us; speedup vs baseline: 2.1639x; 1.0957x over previous
//
#include <hip/hip_runtime.h>

#define NN 100000
#define NE 1000000
#define HID 64
#define BN_EPS 1e-5f

// scan geometry: 4 elems/thread, 256 threads/block -> 1024 elems/block
#define SCAN_EPB 1024
#define SCAN_NB ((NN + SCAN_EPB - 1) / SCAN_EPB)  // 98

// ---------------- CSR build (once, reused by all 3 layers) ----------------

// Histogram AND per-edge rank in one pass: rank[e] = #prior edges with same col.
__global__ void hist_rank_kernel(const int* __restrict__ col, int* __restrict__ deg,
                                 int* __restrict__ rank) {
    int e = blockIdx.x * 256 + threadIdx.x;
    if (e < NE) rank[e] = atomicAdd(&deg[col[e]], 1);
}

__global__ __launch_bounds__(256) void scan_part(const int* __restrict__ deg,
                                                 int* __restrict__ partials) {
    __shared__ int sh[256];
    int t = threadIdx.x;
    int base = blockIdx.x * SCAN_EPB + t * 4;
    int s = 0;
    if (base + 3 < NN) {
        int4 v = *(const int4*)(deg + base);
        s = v.x + v.y + v.z + v.w;
    } else {
#pragma unroll
        for (int i = 0; i < 4; ++i) if (base + i < NN) s += deg[base + i];
    }
    sh[t] = s;
    __syncthreads();
    for (int d = 128; d > 0; d >>= 1) {
        if (t < d) sh[t] += sh[t + d];
        __syncthreads();
    }
    if (t == 0) partials[blockIdx.x] = sh[0];
}

__global__ __launch_bounds__(128) void scan_mid(const int* __restrict__ partials,
                                                int* __restrict__ poff) {
    __shared__ int sh[128];
    int t = threadIdx.x;
    int v = (t < SCAN_NB) ? partials[t] : 0;
    sh[t] = v;
    __syncthreads();
    for (int d = 1; d < 128; d <<= 1) {
        int u = (t >= d) ? sh[t - d] : 0;
        __syncthreads();
        sh[t] += u;
        __syncthreads();
    }
    if (t < SCAN_NB) poff[t] = sh[t] - v;  // exclusive prefix
}

// Local rescan + block offset -> off; also writes dinv (deg already in registers).
__global__ __launch_bounds__(256) void scan_fin(const int* __restrict__ deg,
                                                const int* __restrict__ poff,
                                                int* __restrict__ off,
                                                float* __restrict__ dinv) {
    __shared__ int sh[256];
    int t = threadIdx.x;
    int base = blockIdx.x * SCAN_EPB + t * 4;
    int v0 = 0, v1 = 0, v2 = 0, v3 = 0;
    if (base + 3 < NN) {
        int4 v = *(const int4*)(deg + base);
        v0 = v.x; v1 = v.y; v2 = v.z; v3 = v.w;
    } else {
        if (base + 0 < NN) v0 = deg[base + 0];
        if (base + 1 < NN) v1 = deg[base + 1];
        if (base + 2 < NN) v2 = deg[base + 2];
        if (base + 3 < NN) v3 = deg[base + 3];
    }
    int s = v0 + v1 + v2 + v3;
    sh[t] = s;
    __syncthreads();
    for (int d = 1; d < 256; d <<= 1) {
        int u = (t >= d) ? sh[t - d] : 0;
        __syncthreads();
        sh[t] += u;
        __syncthreads();
    }
    int run = poff[blockIdx.x] + sh[t] - s;
    if (base + 0 < NN) { off[base + 0] = run; run += v0; dinv[base + 0] = rsqrtf((float)(v0 + 1)); }
    if (base + 1 < NN) { off[base + 1] = run; run += v1; dinv[base + 1] = rsqrtf((float)(v1 + 1)); }
    if (base + 2 < NN) { off[base + 2] = run; run += v2; dinv[base + 2] = rsqrtf((float)(v2 + 1)); }
    if (base + 3 < NN) { off[base + 3] = run; run += v3; dinv[base + 3] = rsqrtf((float)(v3 + 1)); }
    if (blockIdx.x == 0 && t == 0) off[NN] = NE;
}

// Atomic-free fill: slot = off[col] + rank[e]. csr entry {src, float_bits(weight)}.
__global__ void fill_kernel(const int* __restrict__ row, const int* __restrict__ col,
                            const int* __restrict__ rank, const int* __restrict__ off,
                            const float* __restrict__ dinv, int2* __restrict__ csr) {
    int e = blockIdx.x * 256 + threadIdx.x;
    if (e >= NE) return;
    int r = row[e], c = col[e];
    int pos = off[c] + rank[e];
    int2 v; v.x = r; v.y = __float_as_int(dinv[r] * dinv[c]);
    csr[pos] = v;
}

// Pad x0 [NN,37] -> xp [NN,40] (zero-pad) so gather rows are float4-addressable.
__global__ void pad_kernel(const float* __restrict__ x, float* __restrict__ xp) {
    int i = blockIdx.x * 256 + threadIdx.x;
    if (i >= NN * 40) return;
    int n = i / 40, k = i - n * 40;
    xp[i] = (k < 37) ? x[n * 37 + k] : 0.f;
}

// ---------------- Fused layer: gather-aggregate (float4, 4 edges/wave) + GEMM + BN/ReLU(+res)
// NC = row chunks of float4 (row stride NC*16 bytes), KREAL = true K (<= NC*4)
template <int NC, int KREAL, bool RES>
__global__ __launch_bounds__(256) void layer_kernel(
    const float* __restrict__ xin, const float* __restrict__ dinv,
    const int* __restrict__ off, const int2* __restrict__ csr,
    const float* __restrict__ W, const float* __restrict__ b,
    const float* __restrict__ gamma, const float* __restrict__ beta,
    const float* __restrict__ mean, const float* __restrict__ var,
    const float* __restrict__ res, float* __restrict__ out) {
    __shared__ float xs[4][NC * 4];
    const int rr = threadIdx.x >> 6;   // node slot in block
    const int l  = threadIdx.x & 63;
    const int eg = l >> 4;             // edge group 0..3
    const int c  = l & 15;             // float4 chunk
    const int n  = blockIdx.x * 4 + rr;
    const float4* __restrict__ x4 = (const float4*)xin;

    float4 acc = make_float4(0.f, 0.f, 0.f, 0.f);
    if (n < NN && c < NC) {
        const size_t rowb = (size_t)n * NC;
        if (eg == 0) {  // self-loop term dinv[n]^2 * x[n]
            float di = dinv[n];
            float4 v = x4[rowb + c];
            float d2 = di * di;
            acc.x = d2 * v.x; acc.y = d2 * v.y; acc.z = d2 * v.z; acc.w = d2 * v.w;
        }
        int p1 = off[n + 1];
        int p  = off[n] + eg;
        // 2x unrolled: 2 gathers in flight per lane-quad -> 8 per wave
        for (; p + 4 < p1; p += 8) {
            int2 e0 = csr[p];
            int2 e1 = csr[p + 4];
            float4 v0 = x4[(size_t)e0.x * NC + c];
            float4 v1 = x4[(size_t)e1.x * NC + c];
            float w0 = __int_as_float(e0.y), w1 = __int_as_float(e1.y);
            acc.x = fmaf(w0, v0.x, acc.x); acc.y = fmaf(w0, v0.y, acc.y);
            acc.z = fmaf(w0, v0.z, acc.z); acc.w = fmaf(w0, v0.w, acc.w);
            acc.x = fmaf(w1, v1.x, acc.x); acc.y = fmaf(w1, v1.y, acc.y);
            acc.z = fmaf(w1, v1.z, acc.z); acc.w = fmaf(w1, v1.w, acc.w);
        }
        if (p < p1) {
            int2 e0 = csr[p];
            float4 v0 = x4[(size_t)e0.x * NC + c];
            float w0 = __int_as_float(e0.y);
            acc.x = fmaf(w0, v0.x, acc.x); acc.y = fmaf(w0, v0.y, acc.y);
            acc.z = fmaf(w0, v0.z, acc.z); acc.w = fmaf(w0, v0.w, acc.w);
        }
    }
    // reduce across the 4 edge groups (lanes l, l^16, l^32, l^48)
#pragma unroll
    for (int m = 16; m <= 32; m <<= 1) {
        acc.x += __shfl_xor(acc.x, m);
        acc.y += __shfl_xor(acc.y, m);
        acc.z += __shfl_xor(acc.z, m);
        acc.w += __shfl_xor(acc.w, m);
    }
    if (n < NN && c < NC && eg == 0) *(float4*)&xs[rr][c << 2] = acc;
    __syncthreads();
    if (n >= NN) return;
    // GEMM + epilogue: j = l
    float a  = gamma[l] * rsqrtf(var[l] + BN_EPS);
    float cc = fmaf(b[l] - mean[l], a, beta[l]);
    float s = 0.f;
#pragma unroll
    for (int k = 0; k < KREAL; ++k) s = fmaf(xs[rr][k], W[k * HID + l], s);
    float v = fmaf(s, a, cc);
    v = fmaxf(v, 0.f);
    if (RES) v += res[(size_t)n * HID + l];
    out[(size_t)n * HID + l] = v;
}

// ---------------- Launch ----------------

static inline size_t align256(size_t x) { return (x + 255) & ~(size_t)255; }

extern "C" void kernel_launch(void* const* d_in, const int* in_sizes, int n_in,
                              void* d_out, int out_size, void* d_ws, size_t ws_size,
                              hipStream_t stream) {
    const float* x0   = (const float*)d_in[0];
    const int*   ei   = (const int*)d_in[1];
    const float* W1   = (const float*)d_in[2];
    const float* W2   = (const float*)d_in[3];
    const float* W3   = (const float*)d_in[4];
    const float* bb   = (const float*)d_in[5];
    const float* gam  = (const float*)d_in[6];
    const float* bet  = (const float*)d_in[7];
    const float* rmn  = (const float*)d_in[8];
    const float* rvr  = (const float*)d_in[9];
    float* out = (float*)d_out;

    char* w = (char*)d_ws;
    int*   deg      = (int*)w;   w += align256((size_t)NN * 4);
    int*   off      = (int*)w;   w += align256((size_t)(NN + 1) * 4);
    float* dinv     = (float*)w; w += align256((size_t)NN * 4);
    int*   rank     = (int*)w;   w += align256((size_t)NE * 4);
    int*   partials = (int*)w;   w += align256((size_t)SCAN_NB * 4);
    int*   poff     = (int*)w;   w += align256((size_t)SCAN_NB * 4);
    int2*  csr      = (int2*)w;  w += align256((size_t)NE * 8);
    float* xpad     = (float*)w; w += align256((size_t)NN * 40 * 4);
    float* hA       = (float*)w; w += align256((size_t)NN * HID * 4);
    float* hB       = (float*)w; w += align256((size_t)NN * HID * 4);

    const int* row = ei;
    const int* col = ei + NE;

    dim3 blk(256);
    dim3 grE((NE + 255) / 256);
    dim3 grN4((NN + 3) / 4);
    dim3 grPad((NN * 40 + 255) / 256);

    // CSR build (9 launches total)
    hipMemsetAsync(deg, 0, (size_t)NN * 4, stream);
    hist_rank_kernel<<<grE, blk, 0, stream>>>(col, deg, rank);
    scan_part<<<SCAN_NB, 256, 0, stream>>>(deg, partials);
    scan_mid<<<1, 128, 0, stream>>>(partials, poff);
    scan_fin<<<SCAN_NB, 256, 0, stream>>>(deg, poff, off, dinv);
    fill_kernel<<<grE, blk, 0, stream>>>(row, col, rank, off, dinv, csr);
    pad_kernel<<<grPad, blk, 0, stream>>>(x0, xpad);

    // Layer 0: padded K=40 rows (real K=37), no residual -> hA
    layer_kernel<10, 37, false><<<grN4, blk, 0, stream>>>(
        xpad, dinv, off, csr, W1, bb + 0, gam + 0, bet + 0, rmn + 0, rvr + 0, nullptr, hA);
    // Layer 1: K=64, residual (+hA) -> hB
    layer_kernel<16, 64, true><<<grN4, blk, 0, stream>>>(
        hA, dinv, off, csr, W2, bb + 64, gam + 64, bet + 64, rmn + 64, rvr + 64, hA, hB);
    // Layer 2: K=64, residual (+hB) -> d_out
    layer_kernel<16, 64, true><<<grN4, blk, 0, stream>>>(
        hB, dinv, off, csr, W3, bb + 128, gam + 128, bet + 128, rmn + 128, rvr + 128, hB, out);
}

// Round 5
// 381.927 us; speedup vs baseline: 2.2434x; 1.0367x over previous
//
#include <hip/hip_runtime.h>
#include <hip/hip_fp16.h>

#define NN 100000
#define NE 1000000
#define HID 64
#define BN_EPS 1e-5f

// scan geometry: 4 elems/thread, 256 threads/block -> 1024 elems/block
#define SCAN_EPB 1024
#define SCAN_NB ((NN + SCAN_EPB - 1) / SCAN_EPB)  // 98

// ---------------- CSR build (once, reused by all 3 layers) ----------------

// Histogram AND per-edge rank in one pass: rank[e] = #prior edges with same col.
__global__ void hist_rank_kernel(const int* __restrict__ col, int* __restrict__ deg,
                                 int* __restrict__ rank) {
    int e = blockIdx.x * 256 + threadIdx.x;
    if (e < NE) rank[e] = atomicAdd(&deg[col[e]], 1);
}

__global__ __launch_bounds__(256) void scan_part(const int* __restrict__ deg,
                                                 int* __restrict__ partials) {
    __shared__ int sh[256];
    int t = threadIdx.x;
    int base = blockIdx.x * SCAN_EPB + t * 4;
    int s = 0;
    if (base + 3 < NN) {
        int4 v = *(const int4*)(deg + base);
        s = v.x + v.y + v.z + v.w;
    } else {
#pragma unroll
        for (int i = 0; i < 4; ++i) if (base + i < NN) s += deg[base + i];
    }
    sh[t] = s;
    __syncthreads();
    for (int d = 128; d > 0; d >>= 1) {
        if (t < d) sh[t] += sh[t + d];
        __syncthreads();
    }
    if (t == 0) partials[blockIdx.x] = sh[0];
}

__global__ __launch_bounds__(128) void scan_mid(const int* __restrict__ partials,
                                                int* __restrict__ poff) {
    __shared__ int sh[128];
    int t = threadIdx.x;
    int v = (t < SCAN_NB) ? partials[t] : 0;
    sh[t] = v;
    __syncthreads();
    for (int d = 1; d < 128; d <<= 1) {
        int u = (t >= d) ? sh[t - d] : 0;
        __syncthreads();
        sh[t] += u;
        __syncthreads();
    }
    if (t < SCAN_NB) poff[t] = sh[t] - v;  // exclusive prefix
}

// Local rescan + block offset -> off; also writes dinv (deg already in registers).
__global__ __launch_bounds__(256) void scan_fin(const int* __restrict__ deg,
                                                const int* __restrict__ poff,
                                                int* __restrict__ off,
                                                float* __restrict__ dinv) {
    __shared__ int sh[256];
    int t = threadIdx.x;
    int base = blockIdx.x * SCAN_EPB + t * 4;
    int v0 = 0, v1 = 0, v2 = 0, v3 = 0;
    if (base + 3 < NN) {
        int4 v = *(const int4*)(deg + base);
        v0 = v.x; v1 = v.y; v2 = v.z; v3 = v.w;
    } else {
        if (base + 0 < NN) v0 = deg[base + 0];
        if (base + 1 < NN) v1 = deg[base + 1];
        if (base + 2 < NN) v2 = deg[base + 2];
        if (base + 3 < NN) v3 = deg[base + 3];
    }
    int s = v0 + v1 + v2 + v3;
    sh[t] = s;
    __syncthreads();
    for (int d = 1; d < 256; d <<= 1) {
        int u = (t >= d) ? sh[t - d] : 0;
        __syncthreads();
        sh[t] += u;
        __syncthreads();
    }
    int run = poff[blockIdx.x] + sh[t] - s;
    if (base + 0 < NN) { off[base + 0] = run; run += v0; dinv[base + 0] = rsqrtf((float)(v0 + 1)); }
    if (base + 1 < NN) { off[base + 1] = run; run += v1; dinv[base + 1] = rsqrtf((float)(v1 + 1)); }
    if (base + 2 < NN) { off[base + 2] = run; run += v2; dinv[base + 2] = rsqrtf((float)(v2 + 1)); }
    if (base + 3 < NN) { off[base + 3] = run; run += v3; dinv[base + 3] = rsqrtf((float)(v3 + 1)); }
    if (blockIdx.x == 0 && t == 0) off[NN] = NE;
}

// Atomic-free, weight-free fill: csr[off[col]+rank] = src. (4B/edge)
__global__ void fill_kernel(const int* __restrict__ row, const int* __restrict__ col,
                            const int* __restrict__ rank, const int* __restrict__ off,
                            int* __restrict__ csr) {
    int e = blockIdx.x * 256 + threadIdx.x;
    if (e >= NE) return;
    csr[off[col[e]] + rank[e]] = row[e];
}

// Scale + pad + fp16-ify x0: xp[n][k] = half(dinv[n]*x0[n][k]) for k<37, 0 for k in [37,40)
__global__ void pad_kernel(const float* __restrict__ x, const float* __restrict__ dinv,
                           __half* __restrict__ xp) {
    int i = blockIdx.x * 256 + threadIdx.x;
    if (i >= NN * 40) return;
    int n = i / 40, k = i - n * 40;
    float v = (k < 37) ? dinv[n] * x[n * 37 + k] : 0.f;
    xp[i] = __float2half_rn(v);
}

// ---------------- Fused layer ----------------
// xin rows: NC chunks of 16B (8 halfs), values pre-scaled by dinv[src].
// agg[n] = dinv[n] * (xin[n] + sum_{src in N(n)} xin[src])   (no per-edge weight!)
// then out = relu(BN(agg @ W + b)) [+ res], res recovered as xin_res/dinv[n].
// W16: also write out16 = half(out*dinv[n]) for next layer's gather. W32: write fp32 out32.
template <int NC, int KREAL, bool RES, bool W16, bool W32>
__global__ __launch_bounds__(256) void layer_kernel(
    const __half* __restrict__ xin, const float* __restrict__ dinv,
    const int* __restrict__ off, const int* __restrict__ csr,
    const float* __restrict__ W, const float* __restrict__ b,
    const float* __restrict__ gamma, const float* __restrict__ beta,
    const float* __restrict__ mean, const float* __restrict__ var,
    const __half* res16, __half* __restrict__ out16, float* __restrict__ out32) {
    __shared__ float xs[4][NC * 8];
    const int rr = threadIdx.x >> 6;   // node slot in block
    const int l  = threadIdx.x & 63;
    const int eg = l >> 3;             // edge group 0..7
    const int c  = l & 7;              // 16B chunk index
    const int n  = blockIdx.x * 4 + rr;
    const float4* __restrict__ x4 = (const float4*)xin;

    float acc[8];
#pragma unroll
    for (int q = 0; q < 8; ++q) acc[q] = 0.f;

#define ADDROW(bits)                                                        \
    do {                                                                    \
        union { float4 f4; __half2 h2[4]; } u_;                             \
        u_.f4 = (bits);                                                     \
        _Pragma("unroll")                                                   \
        for (int q_ = 0; q_ < 4; ++q_) {                                    \
            float2 f_ = __half22float2(u_.h2[q_]);                          \
            acc[2 * q_] += f_.x; acc[2 * q_ + 1] += f_.y;                   \
        }                                                                   \
    } while (0)

    if (n < NN && c < NC) {
        if (eg == 0) ADDROW(x4[(size_t)n * NC + c]);  // self loop
        int p1 = off[n + 1];
        int p  = off[n] + eg;
        for (; p + 8 < p1; p += 16) {  // 2x unrolled: 16 gathers in flight per wave
            int s0 = csr[p], s1 = csr[p + 8];
            float4 v0 = x4[(size_t)s0 * NC + c];
            float4 v1 = x4[(size_t)s1 * NC + c];
            ADDROW(v0);
            ADDROW(v1);
        }
        if (p < p1) ADDROW(x4[(size_t)csr[p] * NC + c]);
    }
#undef ADDROW

    // reduce across the 8 edge groups (lanes l, l^8, l^16, l^32)
#pragma unroll
    for (int m = 8; m <= 32; m <<= 1) {
#pragma unroll
        for (int q = 0; q < 8; ++q) acc[q] += __shfl_xor(acc[q], m);
    }
    float di = (n < NN) ? dinv[n] : 1.f;
    if (n < NN && eg == 0 && c < NC) {
        float4 w0 = make_float4(di * acc[0], di * acc[1], di * acc[2], di * acc[3]);
        float4 w1 = make_float4(di * acc[4], di * acc[5], di * acc[6], di * acc[7]);
        *(float4*)&xs[rr][c * 8]     = w0;
        *(float4*)&xs[rr][c * 8 + 4] = w1;
    }
    __syncthreads();
    if (n >= NN) return;
    // GEMM + epilogue: output column j = l
    float a  = gamma[l] * rsqrtf(var[l] + BN_EPS);
    float cc = fmaf(b[l] - mean[l], a, beta[l]);
    float s = 0.f;
#pragma unroll
    for (int k = 0; k < KREAL; ++k) s = fmaf(xs[rr][k], W[k * HID + l], s);
    float v = fmaf(s, a, cc);
    v = fmaxf(v, 0.f);
    const size_t idx = (size_t)n * HID + l;
    if (RES) v = fmaf(__half2float(res16[idx]), 1.f / di, v);  // unscale residual
    if (W32) out32[idx] = v;
    if (W16) out16[idx] = __float2half_rn(v * di);
}

// ---------------- Launch ----------------

static inline size_t align256(size_t x) { return (x + 255) & ~(size_t)255; }

extern "C" void kernel_launch(void* const* d_in, const int* in_sizes, int n_in,
                              void* d_out, int out_size, void* d_ws, size_t ws_size,
                              hipStream_t stream) {
    const float* x0   = (const float*)d_in[0];
    const int*   ei   = (const int*)d_in[1];
    const float* W1   = (const float*)d_in[2];
    const float* W2   = (const float*)d_in[3];
    const float* W3   = (const float*)d_in[4];
    const float* bb   = (const float*)d_in[5];
    const float* gam  = (const float*)d_in[6];
    const float* bet  = (const float*)d_in[7];
    const float* rmn  = (const float*)d_in[8];
    const float* rvr  = (const float*)d_in[9];
    float* out = (float*)d_out;

    char* w = (char*)d_ws;
    int*    deg      = (int*)w;    w += align256((size_t)NN * 4);
    int*    off      = (int*)w;    w += align256((size_t)(NN + 1) * 4);
    float*  dinv     = (float*)w;  w += align256((size_t)NN * 4);
    int*    rank     = (int*)w;    w += align256((size_t)NE * 4);
    int*    partials = (int*)w;    w += align256((size_t)SCAN_NB * 4);
    int*    poff     = (int*)w;    w += align256((size_t)SCAN_NB * 4);
    int*    csr      = (int*)w;    w += align256((size_t)NE * 4);
    __half* xpad     = (__half*)w; w += align256((size_t)NN * 40 * 2);
    __half* hA16     = (__half*)w; w += align256((size_t)NN * HID * 2);
    __half* hB16     = (__half*)w; w += align256((size_t)NN * HID * 2);

    const int* row = ei;
    const int* col = ei + NE;

    dim3 blk(256);
    dim3 grE((NE + 255) / 256);
    dim3 grN4((NN + 3) / 4);
    dim3 grPad((NN * 40 + 255) / 256);

    // CSR build
    hipMemsetAsync(deg, 0, (size_t)NN * 4, stream);
    hist_rank_kernel<<<grE, blk, 0, stream>>>(col, deg, rank);
    scan_part<<<SCAN_NB, 256, 0, stream>>>(deg, partials);
    scan_mid<<<1, 128, 0, stream>>>(partials, poff);
    scan_fin<<<SCAN_NB, 256, 0, stream>>>(deg, poff, off, dinv);
    fill_kernel<<<grE, blk, 0, stream>>>(row, col, rank, off, csr);
    pad_kernel<<<grPad, blk, 0, stream>>>(x0, dinv, xpad);

    // Layer 0: K=37 (rows padded to 40 halfs, NC=5), no residual -> hA16 only
    layer_kernel<5, 37, false, true, false><<<grN4, blk, 0, stream>>>(
        xpad, dinv, off, csr, W1, bb + 0, gam + 0, bet + 0, rmn + 0, rvr + 0,
        nullptr, hA16, nullptr);
    // Layer 1: K=64 (NC=8), residual from hA16 -> hB16 only
    layer_kernel<8, 64, true, true, false><<<grN4, blk, 0, stream>>>(
        hA16, dinv, off, csr, W2, bb + 64, gam + 64, bet + 64, rmn + 64, rvr + 64,
        hA16, hB16, nullptr);
    // Layer 2: K=64 (NC=8), residual from hB16 -> d_out (fp32)
    layer_kernel<8, 64, true, false, true><<<grN4, blk, 0, stream>>>(
        hB16, dinv, off, csr, W3, bb + 128, gam + 128, bet + 128, rmn + 128, rvr + 128,
        hB16, nullptr, out);
}

// Round 6
// 268.171 us; speedup vs baseline: 3.1950x; 1.4242x over previous
//
#include <hip/hip_runtime.h>
#include <hip/hip_fp16.h>

#define NN 100000
#define NE 1000000
#define HID 64
#define BN_EPS 1e-5f

// scan geometry: 4 elems/thread, 256 threads/block -> 1024 elems/block
#define SCAN_EPB 1024
#define SCAN_NB ((NN + SCAN_EPB - 1) / SCAN_EPB)  // 98

typedef _Float16 hv2 __attribute__((ext_vector_type(2)));
typedef _Float16 hv8 __attribute__((ext_vector_type(8)));

static __device__ __forceinline__ float dot2acc(hv2 a, hv2 b, float c) {
#if __has_builtin(__builtin_amdgcn_fdot2)
    return __builtin_amdgcn_fdot2(a, b, c, false);
#else
    float r = c;
    asm("v_dot2_f32_f16 %0, %1, %2, %0" : "+v"(r) : "v"(a), "v"(b));
    return r;
#endif
}

// ---------------- CSR build (once, reused by all 3 layers) ----------------

// Histogram AND per-edge rank in one pass: rank[e] = #prior edges with same col.
__global__ void hist_rank_kernel(const int* __restrict__ col, int* __restrict__ deg,
                                 int* __restrict__ rank) {
    int e = blockIdx.x * 256 + threadIdx.x;
    if (e < NE) rank[e] = atomicAdd(&deg[col[e]], 1);
}

__global__ __launch_bounds__(256) void scan_part(const int* __restrict__ deg,
                                                 int* __restrict__ partials) {
    __shared__ int sh[256];
    int t = threadIdx.x;
    int base = blockIdx.x * SCAN_EPB + t * 4;
    int s = 0;
    if (base + 3 < NN) {
        int4 v = *(const int4*)(deg + base);
        s = v.x + v.y + v.z + v.w;
    } else {
#pragma unroll
        for (int i = 0; i < 4; ++i) if (base + i < NN) s += deg[base + i];
    }
    sh[t] = s;
    __syncthreads();
    for (int d = 128; d > 0; d >>= 1) {
        if (t < d) sh[t] += sh[t + d];
        __syncthreads();
    }
    if (t == 0) partials[blockIdx.x] = sh[0];
}

__global__ __launch_bounds__(128) void scan_mid(const int* __restrict__ partials,
                                                int* __restrict__ poff) {
    __shared__ int sh[128];
    int t = threadIdx.x;
    int v = (t < SCAN_NB) ? partials[t] : 0;
    sh[t] = v;
    __syncthreads();
    for (int d = 1; d < 128; d <<= 1) {
        int u = (t >= d) ? sh[t - d] : 0;
        __syncthreads();
        sh[t] += u;
        __syncthreads();
    }
    if (t < SCAN_NB) poff[t] = sh[t] - v;  // exclusive prefix
}

// Local rescan + block offset -> off; also writes dinv (deg already in registers).
__global__ __launch_bounds__(256) void scan_fin(const int* __restrict__ deg,
                                                const int* __restrict__ poff,
                                                int* __restrict__ off,
                                                float* __restrict__ dinv) {
    __shared__ int sh[256];
    int t = threadIdx.x;
    int base = blockIdx.x * SCAN_EPB + t * 4;
    int v0 = 0, v1 = 0, v2 = 0, v3 = 0;
    if (base + 3 < NN) {
        int4 v = *(const int4*)(deg + base);
        v0 = v.x; v1 = v.y; v2 = v.z; v3 = v.w;
    } else {
        if (base + 0 < NN) v0 = deg[base + 0];
        if (base + 1 < NN) v1 = deg[base + 1];
        if (base + 2 < NN) v2 = deg[base + 2];
        if (base + 3 < NN) v3 = deg[base + 3];
    }
    int s = v0 + v1 + v2 + v3;
    sh[t] = s;
    __syncthreads();
    for (int d = 1; d < 256; d <<= 1) {
        int u = (t >= d) ? sh[t - d] : 0;
        __syncthreads();
        sh[t] += u;
        __syncthreads();
    }
    int run = poff[blockIdx.x] + sh[t] - s;
    if (base + 0 < NN) { off[base + 0] = run; run += v0; dinv[base + 0] = rsqrtf((float)(v0 + 1)); }
    if (base + 1 < NN) { off[base + 1] = run; run += v1; dinv[base + 1] = rsqrtf((float)(v1 + 1)); }
    if (base + 2 < NN) { off[base + 2] = run; run += v2; dinv[base + 2] = rsqrtf((float)(v2 + 1)); }
    if (base + 3 < NN) { off[base + 3] = run; run += v3; dinv[base + 3] = rsqrtf((float)(v3 + 1)); }
    if (blockIdx.x == 0 && t == 0) off[NN] = NE;
}

// Atomic-free, weight-free fill: csr[off[col]+rank] = src. (4B/edge)
__global__ void fill_kernel(const int* __restrict__ row, const int* __restrict__ col,
                            const int* __restrict__ rank, const int* __restrict__ off,
                            int* __restrict__ csr) {
    int e = blockIdx.x * 256 + threadIdx.x;
    if (e >= NE) return;
    csr[off[col[e]] + rank[e]] = row[e];
}

// Scale + pad + fp16-ify x0: xp[n][k] = half(dinv[n]*x0[n][k]) for k<37, 0 for k in [37,40)
__global__ void pad_kernel(const float* __restrict__ x, const float* __restrict__ dinv,
                           _Float16* __restrict__ xp) {
    int i = blockIdx.x * 256 + threadIdx.x;
    if (i >= NN * 40) return;
    int n = i / 40, k = i - n * 40;
    float v = (k < 37) ? dinv[n] * x[n * 37 + k] : 0.f;
    xp[i] = (_Float16)v;
}

// ---------------- Fused layer ----------------
// Geometry: block = 4 waves; each wave owns 8 consecutive nodes.
//   lane = (slot in [0,8)) * 8 + (c in [0,8));  slot's node = wave_base + slot.
// Gather: 8-lane group accumulates its node's full fp16 row (pk_add), no cross-lane reduce.
// GEMM: thread = output col l; W column preloaded in 32 half2 VGPRs; v_dot2_f32_f16.
// xin rows are dinv-prescaled fp16; agg = di * (self + sum_src) folded into epilogue scale.
template <int NC, int KREAL, bool RES, bool W16, bool W32>
__global__ __launch_bounds__(256) void layer_kernel(
    const _Float16* __restrict__ xin, const float* __restrict__ dinv,
    const int* __restrict__ off, const int* __restrict__ csr,
    const float* __restrict__ W, const float* __restrict__ b,
    const float* __restrict__ gamma, const float* __restrict__ beta,
    const float* __restrict__ mean, const float* __restrict__ var,
    _Float16* __restrict__ out16, float* __restrict__ out32) {
    __shared__ _Float16 xs[4][8][NC * 8];
    const int tid  = threadIdx.x;
    const int w    = tid >> 6;
    const int l    = tid & 63;
    const int slot = l >> 3;
    const int c    = l & 7;
    const int nbase = (blockIdx.x * 4 + w) * 8;   // 3125*4*8 == 100000 exactly
    const hv8* __restrict__ x8 = (const hv8*)xin;

    // ---- W column preload: wc[q] packs rows (2q, 2q+1) of column l ----
    hv2 wc[NC * 4];
#pragma unroll
    for (int q = 0; q < NC * 4; ++q) {
        float w0 = (2 * q     < KREAL) ? W[(2 * q)     * HID + l] : 0.f;
        float w1 = (2 * q + 1 < KREAL) ? W[(2 * q + 1) * HID + l] : 0.f;
        hv2 t = {(_Float16)w0, (_Float16)w1};
        wc[q] = t;
    }

    // ---- gather phase (8-lane group per node, fp16 packed accumulate) ----
    const int n = nbase + slot;
    if (c < NC) {
        hv8 acc = x8[(size_t)n * NC + c];   // self loop (prescaled row)
        int p  = off[n];                    // slot-uniform
        int p1 = off[n + 1];
        for (; p + 1 < p1; p += 2) {        // 2 gathers in flight per lane
            int s0 = csr[p], s1 = csr[p + 1];
            hv8 v0 = x8[(size_t)s0 * NC + c];
            hv8 v1 = x8[(size_t)s1 * NC + c];
            acc += v0;
            acc += v1;
        }
        if (p < p1) acc += x8[(size_t)csr[p] * NC + c];
        *(hv8*)&xs[w][slot][c * 8] = acc;
    }
    __syncthreads();

    // ---- GEMM + epilogue: thread = col l, loop over the wave's 8 nodes ----
    const float aa = gamma[l] * rsqrtf(var[l] + BN_EPS);
    const float cc = fmaf(b[l] - mean[l], aa, beta[l]);
    for (int i = 0; i < 8; ++i) {
        const int ni = nbase + i;
        const hv2* __restrict__ r = (const hv2*)&xs[w][i][0];
        float s = 0.f;
#pragma unroll
        for (int q = 0; q < NC * 4; ++q) s = dot2acc(r[q], wc[q], s);
        const float di = dinv[ni];
        float v = fmaf(s, di * aa, cc);
        v = fmaxf(v, 0.f);
        const size_t idx = (size_t)ni * HID + l;
        if (RES) v = fmaf((float)xin[(size_t)ni * (NC * 8) + l], 1.f / di, v);
        if (W32) out32[idx] = v;
        if (W16) out16[idx] = (_Float16)(v * di);
    }
}

// ---------------- Launch ----------------

static inline size_t align256(size_t x) { return (x + 255) & ~(size_t)255; }

extern "C" void kernel_launch(void* const* d_in, const int* in_sizes, int n_in,
                              void* d_out, int out_size, void* d_ws, size_t ws_size,
                              hipStream_t stream) {
    const float* x0   = (const float*)d_in[0];
    const int*   ei   = (const int*)d_in[1];
    const float* W1   = (const float*)d_in[2];
    const float* W2   = (const float*)d_in[3];
    const float* W3   = (const float*)d_in[4];
    const float* bb   = (const float*)d_in[5];
    const float* gam  = (const float*)d_in[6];
    const float* bet  = (const float*)d_in[7];
    const float* rmn  = (const float*)d_in[8];
    const float* rvr  = (const float*)d_in[9];
    float* out = (float*)d_out;

    char* w = (char*)d_ws;
    int*      deg      = (int*)w;      w += align256((size_t)NN * 4);
    int*      off      = (int*)w;      w += align256((size_t)(NN + 1) * 4);
    float*    dinv     = (float*)w;    w += align256((size_t)NN * 4);
    int*      rank     = (int*)w;      w += align256((size_t)NE * 4);
    int*      partials = (int*)w;      w += align256((size_t)SCAN_NB * 4);
    int*      poff     = (int*)w;      w += align256((size_t)SCAN_NB * 4);
    int*      csr      = (int*)w;      w += align256((size_t)NE * 4);
    _Float16* xpad     = (_Float16*)w; w += align256((size_t)NN * 40 * 2);
    _Float16* hA16     = (_Float16*)w; w += align256((size_t)NN * HID * 2);
    _Float16* hB16     = (_Float16*)w; w += align256((size_t)NN * HID * 2);

    const int* row = ei;
    const int* col = ei + NE;

    dim3 blk(256);
    dim3 grE((NE + 255) / 256);
    dim3 grL(NN / 32);  // 3125 blocks * 32 nodes == 100000 exactly
    dim3 grPad((NN * 40 + 255) / 256);

    // CSR build
    hipMemsetAsync(deg, 0, (size_t)NN * 4, stream);
    hist_rank_kernel<<<grE, blk, 0, stream>>>(col, deg, rank);
    scan_part<<<SCAN_NB, 256, 0, stream>>>(deg, partials);
    scan_mid<<<1, 128, 0, stream>>>(partials, poff);
    scan_fin<<<SCAN_NB, 256, 0, stream>>>(deg, poff, off, dinv);
    fill_kernel<<<grE, blk, 0, stream>>>(row, col, rank, off, csr);
    pad_kernel<<<grPad, blk, 0, stream>>>(x0, dinv, xpad);

    // Layer 0: K=37 (rows padded to 40 halfs, NC=5), no residual -> hA16
    layer_kernel<5, 37, false, true, false><<<grL, blk, 0, stream>>>(
        xpad, dinv, off, csr, W1, bb + 0, gam + 0, bet + 0, rmn + 0, rvr + 0,
        hA16, nullptr);
    // Layer 1: K=64 (NC=8), residual (recovered from hA16) -> hB16
    layer_kernel<8, 64, true, true, false><<<grL, blk, 0, stream>>>(
        hA16, dinv, off, csr, W2, bb + 64, gam + 64, bet + 64, rmn + 64, rvr + 64,
        hB16, nullptr);
    // Layer 2: K=64 (NC=8), residual (recovered from hB16) -> d_out (fp32)
    layer_kernel<8, 64, true, false, true><<<grL, blk, 0, stream>>>(
        hB16, dinv, off, csr, W3, bb + 128, gam + 128, bet + 128, rmn + 128, rvr + 128,
        nullptr, out);
}

// Round 8
// 258.982 us; speedup vs baseline: 3.3084x; 1.0355x over previous
//
#include <hip/hip_runtime.h>
#include <hip/hip_fp16.h>

#define NN 100000
#define NE 1000000
#define HID 64
#define BN_EPS 1e-5f

// scan geometry: 4 elems/thread, 256 threads/block -> 1024 elems/block
#define SCAN_EPB 1024
#define SCAN_NB ((NN + SCAN_EPB - 1) / SCAN_EPB)  // 98

typedef _Float16 hv2 __attribute__((ext_vector_type(2)));
typedef _Float16 hv8 __attribute__((ext_vector_type(8)));

static __device__ __forceinline__ float dot2acc(hv2 a, hv2 b, float c) {
#if __has_builtin(__builtin_amdgcn_fdot2)
    return __builtin_amdgcn_fdot2(a, b, c, false);
#else
    float r = c;
    asm("v_dot2_f32_f16 %0, %1, %2, %0" : "+v"(r) : "v"(a), "v"(b));
    return r;
#endif
}

// ---------------- CSR build (once, reused by all 3 layers) ----------------

// Histogram AND per-edge rank in one pass: rank[e] = #prior edges with same col.
__global__ void hist_rank_kernel(const int* __restrict__ col, int* __restrict__ deg,
                                 unsigned short* __restrict__ rank) {
    int e = blockIdx.x * 256 + threadIdx.x;
    if (e < NE) rank[e] = (unsigned short)atomicAdd(&deg[col[e]], 1);
}

__global__ __launch_bounds__(256) void scan_part(const int* __restrict__ deg,
                                                 int* __restrict__ partials) {
    __shared__ int sh[256];
    int t = threadIdx.x;
    int base = blockIdx.x * SCAN_EPB + t * 4;
    int s = 0;
    if (base + 3 < NN) {
        int4 v = *(const int4*)(deg + base);
        s = v.x + v.y + v.z + v.w;
    } else {
#pragma unroll
        for (int i = 0; i < 4; ++i) if (base + i < NN) s += deg[base + i];
    }
    sh[t] = s;
    __syncthreads();
    for (int d = 128; d > 0; d >>= 1) {
        if (t < d) sh[t] += sh[t + d];
        __syncthreads();
    }
    if (t == 0) partials[blockIdx.x] = sh[0];
}

__global__ __launch_bounds__(128) void scan_mid(const int* __restrict__ partials,
                                                int* __restrict__ poff) {
    __shared__ int sh[128];
    int t = threadIdx.x;
    int v = (t < SCAN_NB) ? partials[t] : 0;
    sh[t] = v;
    __syncthreads();
    for (int d = 1; d < 128; d <<= 1) {
        int u = (t >= d) ? sh[t - d] : 0;
        __syncthreads();
        sh[t] += u;
        __syncthreads();
    }
    if (t < SCAN_NB) poff[t] = sh[t] - v;  // exclusive prefix
}

// Local rescan + block offset -> off; also writes dinv (deg already in registers).
__global__ __launch_bounds__(256) void scan_fin(const int* __restrict__ deg,
                                                const int* __restrict__ poff,
                                                int* __restrict__ off,
                                                float* __restrict__ dinv) {
    __shared__ int sh[256];
    int t = threadIdx.x;
    int base = blockIdx.x * SCAN_EPB + t * 4;
    int v0 = 0, v1 = 0, v2 = 0, v3 = 0;
    if (base + 3 < NN) {
        int4 v = *(const int4*)(deg + base);
        v0 = v.x; v1 = v.y; v2 = v.z; v3 = v.w;
    } else {
        if (base + 0 < NN) v0 = deg[base + 0];
        if (base + 1 < NN) v1 = deg[base + 1];
        if (base + 2 < NN) v2 = deg[base + 2];
        if (base + 3 < NN) v3 = deg[base + 3];
    }
    int s = v0 + v1 + v2 + v3;
    sh[t] = s;
    __syncthreads();
    for (int d = 1; d < 256; d <<= 1) {
        int u = (t >= d) ? sh[t - d] : 0;
        __syncthreads();
        sh[t] += u;
        __syncthreads();
    }
    int run = poff[blockIdx.x] + sh[t] - s;
    if (base + 0 < NN) { off[base + 0] = run; run += v0; dinv[base + 0] = rsqrtf((float)(v0 + 1)); }
    if (base + 1 < NN) { off[base + 1] = run; run += v1; dinv[base + 1] = rsqrtf((float)(v1 + 1)); }
    if (base + 2 < NN) { off[base + 2] = run; run += v2; dinv[base + 2] = rsqrtf((float)(v2 + 1)); }
    if (base + 3 < NN) { off[base + 3] = run; run += v3; dinv[base + 3] = rsqrtf((float)(v3 + 1)); }
    if (blockIdx.x == 0 && t == 0) off[NN] = NE;
}

// Atomic-free, weight-free fill: csr[off[col]+rank] = src. (4B/edge)
__global__ void fill_kernel(const int* __restrict__ row, const int* __restrict__ col,
                            const unsigned short* __restrict__ rank,
                            const int* __restrict__ off, int* __restrict__ csr) {
    int e = blockIdx.x * 256 + threadIdx.x;
    if (e >= NE) return;
    csr[off[col[e]] + (int)rank[e]] = row[e];
}

// Scale + pad + fp16-ify x0: xp[n][k] = half(dinv[n]*x0[n][k]) for k<37, 0 for k in [37,40)
__global__ void pad_kernel(const float* __restrict__ x, const float* __restrict__ dinv,
                           _Float16* __restrict__ xp) {
    int i = blockIdx.x * 256 + threadIdx.x;
    if (i >= NN * 40) return;
    int n = i / 40, k = i - n * 40;
    float v = (k < 37) ? dinv[n] * x[n * 37 + k] : 0.f;
    xp[i] = (_Float16)v;
}

// ---------------- Fused layer ----------------
// Geometry: block = 4 waves; each wave owns 8 consecutive nodes.
//   lane = (slot in [0,8)) * 8 + (c in [0,8));  slot's node = wave_base + slot.
// Gather: 8-lane group accumulates its node's full fp16 row (pk_add), 4-deep unroll
//         -> 32 gathers in flight per wave; no cross-lane reduce.
// GEMM: thread = output col l; W column preloaded in NC*4 half2 VGPRs; v_dot2_f32_f16;
//       LDS row reads are wave-uniform ds_read_b128 (broadcast, conflict-free).
template <int NC, int KREAL, bool RES, bool W16, bool W32>
__global__ __launch_bounds__(256) void layer_kernel(
    const _Float16* __restrict__ xin, const float* __restrict__ dinv,
    const int* __restrict__ off, const int* __restrict__ csr,
    const float* __restrict__ W, const float* __restrict__ b,
    const float* __restrict__ gamma, const float* __restrict__ beta,
    const float* __restrict__ mean, const float* __restrict__ var,
    _Float16* __restrict__ out16, float* __restrict__ out32) {
    __shared__ _Float16 xs[4][8][NC * 8];
    const int tid  = threadIdx.x;
    const int w    = tid >> 6;
    const int l    = tid & 63;
    const int slot = l >> 3;
    const int c    = l & 7;
    const int nbase = (blockIdx.x * 4 + w) * 8;   // 3125*4*8 == 100000 exactly
    const hv8* __restrict__ x8 = (const hv8*)xin;

    // ---- W column preload: wc[q] packs rows (2q, 2q+1) of column l ----
    hv2 wc[NC * 4];
#pragma unroll
    for (int q = 0; q < NC * 4; ++q) {
        float w0 = (2 * q     < KREAL) ? W[(2 * q)     * HID + l] : 0.f;
        float w1 = (2 * q + 1 < KREAL) ? W[(2 * q + 1) * HID + l] : 0.f;
        hv2 t = {(_Float16)w0, (_Float16)w1};
        wc[q] = t;
    }

    // ---- gather phase (8-lane group per node, fp16 packed accumulate) ----
    const int n = nbase + slot;
    if (c < NC) {
        hv8 accA = x8[(size_t)n * NC + c];   // self loop (prescaled row)
        hv8 accB = (hv8)(_Float16)0.f;
        int p  = off[n];                     // slot-uniform
        int p1 = off[n + 1];
        for (; p + 3 < p1; p += 4) {         // 4 gathers in flight per lane
            int s0 = csr[p], s1 = csr[p + 1], s2 = csr[p + 2], s3 = csr[p + 3];
            hv8 v0 = x8[(size_t)s0 * NC + c];
            hv8 v1 = x8[(size_t)s1 * NC + c];
            hv8 v2 = x8[(size_t)s2 * NC + c];
            hv8 v3 = x8[(size_t)s3 * NC + c];
            accA += v0; accB += v1; accA += v2; accB += v3;
        }
        if (p + 1 < p1) {
            hv8 v0 = x8[(size_t)csr[p] * NC + c];
            hv8 v1 = x8[(size_t)csr[p + 1] * NC + c];
            accA += v0; accB += v1;
            p += 2;
        }
        if (p < p1) accA += x8[(size_t)csr[p] * NC + c];
        *(hv8*)&xs[w][slot][c * 8] = accA + accB;
    }
    __syncthreads();

    // ---- GEMM + epilogue: thread = col l, loop over the wave's 8 nodes ----
    const float aa = gamma[l] * rsqrtf(var[l] + BN_EPS);
    const float cc = fmaf(b[l] - mean[l], aa, beta[l]);
    for (int i = 0; i < 8; ++i) {
        const int ni = nbase + i;
        float s = 0.f;
#pragma unroll
        for (int q0 = 0; q0 < NC; ++q0) {
            union { hv8 v; hv2 h[4]; } u;
            u.v = *(const hv8*)&xs[w][i][q0 * 8];   // wave-uniform b128 broadcast
            s = dot2acc(u.h[0], wc[q0 * 4 + 0], s);
            s = dot2acc(u.h[1], wc[q0 * 4 + 1], s);
            s = dot2acc(u.h[2], wc[q0 * 4 + 2], s);
            s = dot2acc(u.h[3], wc[q0 * 4 + 3], s);
        }
        const float di = dinv[ni];
        float v = fmaf(s, di * aa, cc);
        v = fmaxf(v, 0.f);
        const size_t idx = (size_t)ni * HID + l;
        if (RES) v = fmaf((float)xin[(size_t)ni * (NC * 8) + l], 1.f / di, v);
        if (W32) out32[idx] = v;
        if (W16) out16[idx] = (_Float16)(v * di);
    }
}

// ---------------- Launch ----------------

static inline size_t align256(size_t x) { return (x + 255) & ~(size_t)255; }

extern "C" void kernel_launch(void* const* d_in, const int* in_sizes, int n_in,
                              void* d_out, int out_size, void* d_ws, size_t ws_size,
                              hipStream_t stream) {
    const float* x0   = (const float*)d_in[0];
    const int*   ei   = (const int*)d_in[1];
    const float* W1   = (const float*)d_in[2];
    const float* W2   = (const float*)d_in[3];
    const float* W3   = (const float*)d_in[4];
    const float* bb   = (const float*)d_in[5];
    const float* gam  = (const float*)d_in[6];
    const float* bet  = (const float*)d_in[7];
    const float* rmn  = (const float*)d_in[8];
    const float* rvr  = (const float*)d_in[9];
    float* out = (float*)d_out;

    char* w = (char*)d_ws;
    int*      deg      = (int*)w;      w += align256((size_t)NN * 4);
    int*      off      = (int*)w;      w += align256((size_t)(NN + 1) * 4);
    float*    dinv     = (float*)w;    w += align256((size_t)NN * 4);
    unsigned short* rank = (unsigned short*)w; w += align256((size_t)NE * 2);
    int*      partials = (int*)w;      w += align256((size_t)SCAN_NB * 4);
    int*      poff     = (int*)w;      w += align256((size_t)SCAN_NB * 4);
    int*      csr      = (int*)w;      w += align256((size_t)NE * 4);
    _Float16* xpad     = (_Float16*)w; w += align256((size_t)NN * 40 * 2);
    _Float16* hA16     = (_Float16*)w; w += align256((size_t)NN * HID * 2);
    _Float16* hB16     = (_Float16*)w; w += align256((size_t)NN * HID * 2);

    const int* row = ei;
    const int* col = ei + NE;

    dim3 blk(256);
    dim3 grE((NE + 255) / 256);
    dim3 grL(NN / 32);  // 3125 blocks * 32 nodes == 100000 exactly
    dim3 grPad((NN * 40 + 255) / 256);

    // CSR build
    hipMemsetAsync(deg, 0, (size_t)NN * 4, stream);
    hist_rank_kernel<<<grE, blk, 0, stream>>>(col, deg, rank);
    scan_part<<<SCAN_NB, 256, 0, stream>>>(deg, partials);
    scan_mid<<<1, 128, 0, stream>>>(partials, poff);
    scan_fin<<<SCAN_NB, 256, 0, stream>>>(deg, poff, off, dinv);
    fill_kernel<<<grE, blk, 0, stream>>>(row, col, rank, off, csr);
    pad_kernel<<<grPad, blk, 0, stream>>>(x0, dinv, xpad);

    // Layer 0: K=37 (rows padded to 40 halfs, NC=5), no residual -> hA16
    layer_kernel<5, 37, false, true, false><<<grL, blk, 0, stream>>>(
        xpad, dinv, off, csr, W1, bb + 0, gam + 0, bet + 0, rmn + 0, rvr + 0,
        hA16, nullptr);
    // Layer 1: K=64 (NC=8), residual (recovered from hA16) -> hB16
    layer_kernel<8, 64, true, true, false><<<grL, blk, 0, stream>>>(
        hA16, dinv, off, csr, W2, bb + 64, gam + 64, bet + 64, rmn + 64, rvr + 64,
        hB16, nullptr);
    // Layer 2: K=64 (NC=8), residual (recovered from hB16) -> d_out (fp32)
    layer_kernel<8, 64, true, false, true><<<grL, blk, 0, stream>>>(
        hB16, dinv, off, csr, W3, bb + 128, gam + 128, bet + 128, rmn + 128, rvr + 128,
        nullptr, out);
}